// Round 22
// baseline (752.037 us; speedup 1.0000x reference)
//
#include <hip/hip_runtime.h>
#include <math.h>

#define CC 20
#define BB 256
#define HH 10
#define SS 64
#define AA 16
#define HD 128
#define RH 64
#define CBR (CC*BB)      // 5120 rows
#define NSNN 15
#define RT 4             // rows per block, ONE WAVE per row

// Replicate npy_logaddexpf(u, 0.f): float32 chain, expf/log1pf at
// correctly-rounded level via f64 internals. (Verified bit-exact rounds 4-21.)
__device__ __forceinline__ float softplus_np(float u) {
    if (u > 0.0f) {
        float ef = (float)exp((double)(-u));
        float l1 = (float)log1p((double)ef);
        return __fadd_rn(u, l1);
    } else if (u < 0.0f) {
        float ef = (float)exp((double)u);
        return (float)log1p((double)ef);
    } else {
        return 0.69314718055994530942f;
    }
}

// ROUND-15 STRUCTURE + float4 LDS BROADCAST READS (this round's only change).
//
// One block = RT(=4) rows, ONE horizon step h, one 64-lane WAVE per row,
// reward for step h fused in. Lane owns hidden units j=lane and j=lane+64
// (2-way ILP). ZERO __syncthreads: all LDS producer->consumer pairs are
// intra-wave, lgkmcnt-ordered. launch_bounds (256,4) => 64-VGPR target
// (empirical cap = 256/arg; r14 (256,8)->32 spilled, r15 (256,4)->48 clean).
//
// This round: the ~500 scalar ds_read_b32 broadcast reads per wave-step
// (se 64, cur 256, decode 128, reward ~210) vectorize 4x to ds_read_b128 —
// pure issue-slot/lgkm-dependency reduction; FMA consumption order stays
// strictly ascending-i in every chain -> bit-exact. All LDS row bases are
// 16B-aligned.
//
// Search map (exhausted — do NOT redo): h-fusion dead x6 (r5/r7/r11/r13/
// r18/r20-crash); W2 batch-prefetch r16 +5%; adjacent-unit remap r17 +31%;
// RT=2-in-thread r9 regress.
//
// All dots are single sequential-k fmaf chains; elementwise ops separately
// rounded (__f*_rn) — bit-exact vs np-f32 (absmax 0.0, rounds 4-21). W2
// k-loops pinned rolled (#pragma unroll 1), per-k skip, loads AFTER the
// branch; t-loops fully unrolled. fmaf(sv in {0,1}, w, acc) with sv=0 is
// an exact identity; per-t chains stay k-ascending.
__global__ __launch_bounds__(256, 4) void world_kernel(
    int h,
    const float* __restrict__ current_state,   // [B,S]
    const float* __restrict__ actions,         // [C,B,H,A]
    const float* __restrict__ noise,           // [C,B,H,S]
    const float* __restrict__ Wse, const float* __restrict__ bse,
    const float* __restrict__ Wae, const float* __restrict__ bae,
    const float* __restrict__ W1,  const float* __restrict__ b1,
    const float* __restrict__ W2,  const float* __restrict__ b2,
    const float* __restrict__ Wdec, const float* __restrict__ bdec,
    const float* __restrict__ Wunc, const float* __restrict__ bunc,
    const float* __restrict__ Wr1, const float* __restrict__ br1,
    const float* __restrict__ Wr2, const float* __restrict__ br2,
    const float* __restrict__ Wr3, const float* __restrict__ br3,
    float* __restrict__ states,                // [H, CB, S]
    float* __restrict__ cum)                   // [CB]
{
    const int r    = threadIdx.x >> 6;         // row (wave) within block
    const int lane = threadIdx.x & 63;
    const int cb   = blockIdx.x * RT + r;

    __shared__ float s_state[RT][SS];
    __shared__ float s_sae[RT][2*HD];
    __shared__ float s_mem2[RT][HD];
    __shared__ float s_x[RT][SS + AA];
    __shared__ float s_h[RT][RH];
    __shared__ float s_h2[RT][RH];

    s_state[r][lane] = (h == 0) ? current_state[(size_t)(cb % BB)*SS + lane]
                                : states[((size_t)(h-1)*CBR + cb)*SS + lane];
    // intra-wave LDS dep: hardware lgkmcnt orders write->read, no barrier

    // ---- se = relu(state @ Wse + bse): two sequential-k chains (units
    // lane, lane+64); LDS broadcast read 4-at-a-time, FMA order ascending i
    float a0 = 0.0f, a1 = 0.0f;
    {
        const float* p = Wse + lane;
        for (int i4 = 0; i4 < SS/4; i4++) {
            float4 st = *(const float4*)&s_state[r][i4*4];
            int i = i4*4;
            a0 = fmaf(st.x, p[(i+0)*HD],      a0);
            a1 = fmaf(st.x, p[(i+0)*HD + 64], a1);
            a0 = fmaf(st.y, p[(i+1)*HD],      a0);
            a1 = fmaf(st.y, p[(i+1)*HD + 64], a1);
            a0 = fmaf(st.z, p[(i+2)*HD],      a0);
            a1 = fmaf(st.z, p[(i+2)*HD + 64], a1);
            a0 = fmaf(st.w, p[(i+3)*HD],      a0);
            a1 = fmaf(st.w, p[(i+3)*HD + 64], a1);
        }
    }
    float se0 = fmaxf(__fadd_rn(a0, bse[lane]),      0.0f);
    float se1 = fmaxf(__fadd_rn(a1, bse[64 + lane]), 0.0f);

    // ---- ae = relu(act @ Wae + bae)
    const float* act = actions + ((size_t)cb*HH + h)*AA;
    float e0 = 0.0f, e1 = 0.0f;
    {
        const float* p = Wae + lane;
        for (int i = 0; i < AA; i++) {
            float av = act[i];
            e0 = fmaf(av, p[i*HD],      e0);
            e1 = fmaf(av, p[i*HD + 64], e1);
        }
    }
    float ae0 = fmaxf(__fadd_rn(e0, bae[lane]),      0.0f);
    float ae1 = fmaxf(__fadd_rn(e1, bae[64 + lane]), 0.0f);

    s_sae[r][lane]            = se0;
    s_sae[r][64 + lane]       = se1;
    s_sae[r][HD + lane]       = ae0;
    s_sae[r][HD + 64 + lane]  = ae1;

    // ---- cur = concat(se, ae) @ W1 + b1: two 256-chains; float4 LDS reads
    float c0 = 0.0f, c1 = 0.0f;
    {
        const float* p = W1 + lane;
        for (int i4 = 0; i4 < (2*HD)/4; i4++) {
            float4 v = *(const float4*)&s_sae[r][i4*4];
            int i = i4*4;
            c0 = fmaf(v.x, p[(i+0)*HD],      c0);
            c1 = fmaf(v.x, p[(i+0)*HD + 64], c1);
            c0 = fmaf(v.y, p[(i+1)*HD],      c0);
            c1 = fmaf(v.y, p[(i+1)*HD + 64], c1);
            c0 = fmaf(v.z, p[(i+2)*HD],      c0);
            c1 = fmaf(v.z, p[(i+2)*HD + 64], c1);
            c0 = fmaf(v.w, p[(i+3)*HD],      c0);
            c1 = fmaf(v.w, p[(i+3)*HD + 64], c1);
        }
    }
    const float cur0 = __fadd_rn(c0, b1[lane]);
    const float cur1 = __fadd_rn(c1, b1[64 + lane]);

    // ---- mem1 recurrence -> 15-bit spike masks, both units (exact order)
    unsigned mask0 = 0u, mask1 = 0u;
    {
        float m1a = 0.0f, m1b = 0.0f;
        #pragma unroll
        for (int t = 0; t < NSNN; t++) {
            float spa = (__fsub_rn(m1a, 1.0f) > 0.0f) ? 1.0f : 0.0f;
            m1a = __fsub_rn(__fadd_rn(__fmul_rn(0.9f, m1a), cur0), spa);
            if (__fsub_rn(m1a, 1.0f) > 0.0f) mask0 |= (1u << t);
            float spb = (__fsub_rn(m1b, 1.0f) > 0.0f) ? 1.0f : 0.0f;
            m1b = __fsub_rn(__fadd_rn(__fmul_rn(0.9f, m1b), cur1), spb);
            if (__fsub_rn(m1b, 1.0f) > 0.0f) mask1 |= (1u << t);
        }
    }
    // lane k's mask0/mask1 ARE units k / 64+k — readlane, no LDS trip.

    // ---- cur2[t] = spk[t] @ W2 for both units, one k-ascending pass
    float c2a[NSNN], c2b[NSNN];
    #pragma unroll
    for (int t = 0; t < NSNN; t++) { c2a[t] = 0.0f; c2b[t] = 0.0f; }

    const float* W2j = W2 + lane;
    #pragma unroll 1
    for (int k = 0; k < 64; k++) {
        unsigned m = (unsigned)__builtin_amdgcn_readlane((int)mask0, k);
        if (m == 0u) continue;           // wave-uniform scalar branch
        const float* p = W2j + (size_t)k * HD;
        float wa = p[0];
        float wb = p[64];
        #pragma unroll
        for (int t = 0; t < NSNN; t++) {
            float sv = __uint_as_float(((m >> t) & 1u) * 0x3f800000u);
            c2a[t] = fmaf(sv, wa, c2a[t]);
            c2b[t] = fmaf(sv, wb, c2b[t]);
        }
    }
    #pragma unroll 1
    for (int k = 0; k < 64; k++) {
        unsigned m = (unsigned)__builtin_amdgcn_readlane((int)mask1, k);
        if (m == 0u) continue;
        const float* p = W2j + (size_t)(64 + k) * HD;
        float wa = p[0];
        float wb = p[64];
        #pragma unroll
        for (int t = 0; t < NSNN; t++) {
            float sv = __uint_as_float(((m >> t) & 1u) * 0x3f800000u);
            c2a[t] = fmaf(sv, wa, c2a[t]);
            c2b[t] = fmaf(sv, wb, c2b[t]);
        }
    }

    // ---- mem2 recurrence, both units (exact op order)
    {
        const float b2a = b2[lane], b2b = b2[64 + lane];
        float m2a = 0.0f, m2b = 0.0f;
        #pragma unroll
        for (int t = 0; t < NSNN; t++) {
            float ca = __fadd_rn(c2a[t], b2a);
            float spa = (__fsub_rn(m2a, 1.0f) > 0.0f) ? 1.0f : 0.0f;
            m2a = __fsub_rn(__fadd_rn(__fmul_rn(0.9f, m2a), ca), spa);
            float cbv = __fadd_rn(c2b[t], b2b);
            float spb = (__fsub_rn(m2b, 1.0f) > 0.0f) ? 1.0f : 0.0f;
            m2b = __fsub_rn(__fadd_rn(__fmul_rn(0.9f, m2b), cbv), spb);
        }
        s_mem2[r][lane]      = m2a;
        s_mem2[r][64 + lane] = m2b;
    }

    // ---- decode: lane computes mean[lane] AND u[lane]; float4 LDS reads
    float dm = 0.0f, du = 0.0f;
    {
        const float* pd = Wdec + lane;
        const float* pu = Wunc + lane;
        for (int n4 = 0; n4 < HD/4; n4++) {
            float4 mv = *(const float4*)&s_mem2[r][n4*4];
            int n = n4*4;
            dm = fmaf(mv.x, pd[(n+0)*SS], dm);
            du = fmaf(mv.x, pu[(n+0)*SS], du);
            dm = fmaf(mv.y, pd[(n+1)*SS], dm);
            du = fmaf(mv.y, pu[(n+1)*SS], du);
            dm = fmaf(mv.z, pd[(n+2)*SS], dm);
            du = fmaf(mv.z, pu[(n+2)*SS], du);
            dm = fmaf(mv.w, pd[(n+3)*SS], dm);
            du = fmaf(mv.w, pu[(n+3)*SS], du);
        }
    }
    float mean = __fadd_rn(dm, bdec[lane]);
    float u    = __fadd_rn(du, bunc[lane]);

    // ---- sample next state
    float var = softplus_np(u);
    float sv  = sqrtf(__fadd_rn(var, 1e-8f));
    float nz  = noise[((size_t)cb*HH + h)*SS + lane];
    float ns  = __fadd_rn(mean, __fmul_rn(nz, sv));
    states[((size_t)h*CBR + cb)*SS + lane] = ns;

    // ---- reward for step h (fused): x = [ns, act]; float4 LDS reads
    s_x[r][lane] = ns;
    if (lane < AA) s_x[r][SS + lane] = act[lane];

    float ra = 0.0f;
    {
        for (int i4 = 0; i4 < (SS + AA)/4; i4++) {
            float4 xv = *(const float4*)&s_x[r][i4*4];
            int i = i4*4;
            ra = fmaf(xv.x, Wr1[(i+0)*RH + lane], ra);
            ra = fmaf(xv.y, Wr1[(i+1)*RH + lane], ra);
            ra = fmaf(xv.z, Wr1[(i+2)*RH + lane], ra);
            ra = fmaf(xv.w, Wr1[(i+3)*RH + lane], ra);
        }
    }
    s_h[r][lane] = fmaxf(__fadd_rn(ra, br1[lane]), 0.0f);

    float rg = 0.0f;
    {
        for (int i4 = 0; i4 < RH/4; i4++) {
            float4 hv = *(const float4*)&s_h[r][i4*4];
            int i = i4*4;
            rg = fmaf(hv.x, Wr2[(i+0)*RH + lane], rg);
            rg = fmaf(hv.y, Wr2[(i+1)*RH + lane], rg);
            rg = fmaf(hv.z, Wr2[(i+2)*RH + lane], rg);
            rg = fmaf(hv.w, Wr2[(i+3)*RH + lane], rg);
        }
    }
    s_h2[r][lane] = fmaxf(__fadd_rn(rg, br2[lane]), 0.0f);

    // fold r_h (redundant across lanes via broadcast reads; lane 0 commits).
    // cum accumulates across the 10 dispatches in ascending-h order — the
    // same sequential __fadd_rn chain as the reference.
    float rr = 0.0f;
    {
        for (int k4 = 0; k4 < RH/4; k4++) {
            float4 h2v = *(const float4*)&s_h2[r][k4*4];
            int k = k4*4;
            rr = fmaf(h2v.x, Wr3[k+0], rr);
            rr = fmaf(h2v.y, Wr3[k+1], rr);
            rr = fmaf(h2v.z, Wr3[k+2], rr);
            rr = fmaf(h2v.w, Wr3[k+3], rr);
        }
    }
    rr = __fadd_rn(rr, br3[0]);
    if (lane == 0)
        cum[cb] = (h == 0) ? rr : __fadd_rn(cum[cb], rr);
}

// One block per batch element b: f32 argmax over C (strict > = first max),
// gather best action. (Bit-exact, unchanged.)
__global__ __launch_bounds__(64) void select_kernel(
    const float* __restrict__ cum,      // [CB], cb = c*B + b
    const float* __restrict__ actions,  // [C,B,H,A]
    float* __restrict__ out)            // [B*H*A] actions then [B] values
{
    const int b = blockIdx.x;
    const int j = threadIdx.x;
    __shared__ int s_c;

    if (j == 0) {
        float best = cum[b];            // c = 0
        int bc = 0;
        for (int c = 1; c < CC; c++) {
            float v = cum[(size_t)c*BB + b];
            if (v > best) { best = v; bc = c; }
        }
        s_c = bc;
        out[(size_t)BB*HH*AA + b] = best;
    }
    __syncthreads();
    const int bc = s_c;
    const float* src = actions + ((size_t)bc*BB + b)*HH*AA;
    for (int i = j; i < HH*AA; i += 64) out[(size_t)b*HH*AA + i] = src[i];
}

extern "C" void kernel_launch(void* const* d_in, const int* in_sizes, int n_in,
                              void* d_out, int out_size, void* d_ws, size_t ws_size,
                              hipStream_t stream)
{
    const float* current_state = (const float*)d_in[0];
    const float* actions = (const float*)d_in[1];
    const float* noise   = (const float*)d_in[2];
    const float* Wse = (const float*)d_in[3];
    const float* bse = (const float*)d_in[4];
    const float* Wae = (const float*)d_in[5];
    const float* bae = (const float*)d_in[6];
    const float* W1  = (const float*)d_in[7];
    const float* b1  = (const float*)d_in[8];
    const float* W2  = (const float*)d_in[9];
    const float* b2  = (const float*)d_in[10];
    const float* Wdec = (const float*)d_in[11];
    const float* bdec = (const float*)d_in[12];
    const float* Wunc = (const float*)d_in[13];
    const float* bunc = (const float*)d_in[14];
    const float* Wr1 = (const float*)d_in[15];
    const float* br1 = (const float*)d_in[16];
    const float* Wr2 = (const float*)d_in[17];
    const float* br2 = (const float*)d_in[18];
    const float* Wr3 = (const float*)d_in[19];
    const float* br3 = (const float*)d_in[20];

    float* states = (float*)d_ws;                       // 10*5120*64 f32 = 13.1 MB
    float* cum    = states + (size_t)HH*CBR*SS;         // 5120 f32

    for (int h = 0; h < HH; h++) {
        world_kernel<<<CBR/RT, RT*64, 0, stream>>>(h, current_state, actions, noise,
            Wse, bse, Wae, bae, W1, b1, W2, b2, Wdec, bdec, Wunc, bunc,
            Wr1, br1, Wr2, br2, Wr3, br3, states, cum);
    }
    select_kernel<<<BB, 64, 0, stream>>>(cum, actions, (float*)d_out);
}

// Round 23
// 743.544 us; speedup vs baseline: 1.0114x; 1.0114x over previous
//
#include <hip/hip_runtime.h>
#include <math.h>

#define CC 20
#define BB 256
#define HH 10
#define SS 64
#define AA 16
#define HD 128
#define RH 64
#define CBR (CC*BB)      // 5120 rows
#define NSNN 15
#define RT 4             // rows per block, ONE WAVE per row

// Replicate npy_logaddexpf(u, 0.f): float32 chain, expf/log1pf at
// correctly-rounded level via f64 internals. (Verified bit-exact rounds 4-22.)
__device__ __forceinline__ float softplus_np(float u) {
    if (u > 0.0f) {
        float ef = (float)exp((double)(-u));
        float l1 = (float)log1p((double)ef);
        return __fadd_rn(u, l1);
    } else if (u < 0.0f) {
        float ef = (float)exp((double)u);
        return (float)log1p((double)ef);
    } else {
        return 0.69314718055994530942f;
    }
}

// ROUND-15 OPTIMUM, FINAL (744.0 us; reproduced r15, r19, r21).
//
// One block = RT(=4) rows, ONE horizon step h, one 64-lane WAVE per row,
// reward for step h fused in. Lane owns hidden units j=lane and j=lane+64
// (2-way ILP in every chain). ZERO __syncthreads: all LDS producer->consumer
// pairs are intra-wave, ordered by hardware lgkmcnt.
//
// launch_bounds (256,4) => 64-VGPR allocator target (empirical: cap=256/arg;
// (256,8)->32 spilled r14; (256,4)->48 clean r15). 48 VGPR -> full-residency
// tier: all 5 blocks/CU resident, one generation.
//
// Search map (EXHAUSTED — do not redo):
//  - h-FUSION DEAD x6: r5(plain/196VGPR), r7(unroll-pin/212), r11(multi-
//    noinline/serialized), r13(sched_barrier/236), r18(pressure-cap/spilled
//    2.5GB), r20(single-noinline+LDS-statics/CRASH).
//  - Refinements from R15, all regressed: r16 batch-prefetch (+5%),
//    r17 adjacent-unit float2 remap (+31%), r9 fat-threads, r22 float4-LDS
//    (+1%, VGPR 56 -> occupancy 40->32%).
//
// All dots are single sequential-k fmaf chains; elementwise ops separately
// rounded (__f*_rn) — bit-exact vs np-f32 (the np reference is f32 with
// sequential-k single-accumulator dots; absmax 0.0 rounds 4-22). W2 k-loops
// pinned rolled (#pragma unroll 1), per-k skip, loads AFTER the branch;
// t-loops fully unrolled so accumulators stay in registers. fmaf(sv in
// {0,1}, w, acc) with sv=0 is an exact identity, so skipping m==0 units
// removes only exact-zero terms; per-t chains stay k-ascending ->
// bit-identical to the reference.
__global__ __launch_bounds__(256, 4) void world_kernel(
    int h,
    const float* __restrict__ current_state,   // [B,S]
    const float* __restrict__ actions,         // [C,B,H,A]
    const float* __restrict__ noise,           // [C,B,H,S]
    const float* __restrict__ Wse, const float* __restrict__ bse,
    const float* __restrict__ Wae, const float* __restrict__ bae,
    const float* __restrict__ W1,  const float* __restrict__ b1,
    const float* __restrict__ W2,  const float* __restrict__ b2,
    const float* __restrict__ Wdec, const float* __restrict__ bdec,
    const float* __restrict__ Wunc, const float* __restrict__ bunc,
    const float* __restrict__ Wr1, const float* __restrict__ br1,
    const float* __restrict__ Wr2, const float* __restrict__ br2,
    const float* __restrict__ Wr3, const float* __restrict__ br3,
    float* __restrict__ states,                // [H, CB, S]
    float* __restrict__ cum)                   // [CB]
{
    const int r    = threadIdx.x >> 6;         // row (wave) within block
    const int lane = threadIdx.x & 63;
    const int cb   = blockIdx.x * RT + r;

    __shared__ float s_state[RT][SS];
    __shared__ float s_sae[RT][2*HD];
    __shared__ float s_mem2[RT][HD];
    __shared__ float s_x[RT][SS + AA];
    __shared__ float s_h[RT][RH];
    __shared__ float s_h2[RT][RH];

    s_state[r][lane] = (h == 0) ? current_state[(size_t)(cb % BB)*SS + lane]
                                : states[((size_t)(h-1)*CBR + cb)*SS + lane];
    // intra-wave LDS dep: hardware lgkmcnt orders write->read, no barrier

    // ---- se = relu(state @ Wse + bse): two sequential-k chains (units
    // lane, lane+64), interleaved for ILP — per-chain op order unchanged
    float a0 = 0.0f, a1 = 0.0f;
    {
        const float* p = Wse + lane;
        for (int i = 0; i < SS; i++) {
            float st = s_state[r][i];                    // broadcast read
            a0 = fmaf(st, p[i*HD],      a0);
            a1 = fmaf(st, p[i*HD + 64], a1);
        }
    }
    float se0 = fmaxf(__fadd_rn(a0, bse[lane]),      0.0f);
    float se1 = fmaxf(__fadd_rn(a1, bse[64 + lane]), 0.0f);

    // ---- ae = relu(act @ Wae + bae)
    const float* act = actions + ((size_t)cb*HH + h)*AA;
    float e0 = 0.0f, e1 = 0.0f;
    {
        const float* p = Wae + lane;
        for (int i = 0; i < AA; i++) {
            float av = act[i];
            e0 = fmaf(av, p[i*HD],      e0);
            e1 = fmaf(av, p[i*HD + 64], e1);
        }
    }
    float ae0 = fmaxf(__fadd_rn(e0, bae[lane]),      0.0f);
    float ae1 = fmaxf(__fadd_rn(e1, bae[64 + lane]), 0.0f);

    s_sae[r][lane]            = se0;
    s_sae[r][64 + lane]       = se1;
    s_sae[r][HD + lane]       = ae0;
    s_sae[r][HD + 64 + lane]  = ae1;

    // ---- cur = concat(se, ae) @ W1 + b1: two 256-chains, interleaved
    float c0 = 0.0f, c1 = 0.0f;
    {
        const float* p = W1 + lane;
        for (int i = 0; i < 2*HD; i++) {
            float v = s_sae[r][i];                       // broadcast read
            c0 = fmaf(v, p[i*HD],      c0);
            c1 = fmaf(v, p[i*HD + 64], c1);
        }
    }
    const float cur0 = __fadd_rn(c0, b1[lane]);
    const float cur1 = __fadd_rn(c1, b1[64 + lane]);

    // ---- mem1 recurrence -> 15-bit spike masks, both units (exact order)
    unsigned mask0 = 0u, mask1 = 0u;
    {
        float m1a = 0.0f, m1b = 0.0f;
        #pragma unroll
        for (int t = 0; t < NSNN; t++) {
            float spa = (__fsub_rn(m1a, 1.0f) > 0.0f) ? 1.0f : 0.0f;
            m1a = __fsub_rn(__fadd_rn(__fmul_rn(0.9f, m1a), cur0), spa);
            if (__fsub_rn(m1a, 1.0f) > 0.0f) mask0 |= (1u << t);
            float spb = (__fsub_rn(m1b, 1.0f) > 0.0f) ? 1.0f : 0.0f;
            m1b = __fsub_rn(__fadd_rn(__fmul_rn(0.9f, m1b), cur1), spb);
            if (__fsub_rn(m1b, 1.0f) > 0.0f) mask1 |= (1u << t);
        }
    }
    // lane k's mask0/mask1 ARE units k / 64+k — readlane, no LDS trip.

    // ---- cur2[t] = spk[t] @ W2 for both units, one k-ascending pass
    float c2a[NSNN], c2b[NSNN];
    #pragma unroll
    for (int t = 0; t < NSNN; t++) { c2a[t] = 0.0f; c2b[t] = 0.0f; }

    const float* W2j = W2 + lane;
    #pragma unroll 1
    for (int k = 0; k < 64; k++) {
        unsigned m = (unsigned)__builtin_amdgcn_readlane((int)mask0, k);
        if (m == 0u) continue;           // wave-uniform scalar branch
        const float* p = W2j + (size_t)k * HD;
        float wa = p[0];
        float wb = p[64];
        #pragma unroll
        for (int t = 0; t < NSNN; t++) {
            float sv = __uint_as_float(((m >> t) & 1u) * 0x3f800000u);
            c2a[t] = fmaf(sv, wa, c2a[t]);
            c2b[t] = fmaf(sv, wb, c2b[t]);
        }
    }
    #pragma unroll 1
    for (int k = 0; k < 64; k++) {
        unsigned m = (unsigned)__builtin_amdgcn_readlane((int)mask1, k);
        if (m == 0u) continue;
        const float* p = W2j + (size_t)(64 + k) * HD;
        float wa = p[0];
        float wb = p[64];
        #pragma unroll
        for (int t = 0; t < NSNN; t++) {
            float sv = __uint_as_float(((m >> t) & 1u) * 0x3f800000u);
            c2a[t] = fmaf(sv, wa, c2a[t]);
            c2b[t] = fmaf(sv, wb, c2b[t]);
        }
    }

    // ---- mem2 recurrence, both units (exact op order)
    {
        const float b2a = b2[lane], b2b = b2[64 + lane];
        float m2a = 0.0f, m2b = 0.0f;
        #pragma unroll
        for (int t = 0; t < NSNN; t++) {
            float ca = __fadd_rn(c2a[t], b2a);
            float spa = (__fsub_rn(m2a, 1.0f) > 0.0f) ? 1.0f : 0.0f;
            m2a = __fsub_rn(__fadd_rn(__fmul_rn(0.9f, m2a), ca), spa);
            float cbv = __fadd_rn(c2b[t], b2b);
            float spb = (__fsub_rn(m2b, 1.0f) > 0.0f) ? 1.0f : 0.0f;
            m2b = __fsub_rn(__fadd_rn(__fmul_rn(0.9f, m2b), cbv), spb);
        }
        s_mem2[r][lane]      = m2a;
        s_mem2[r][64 + lane] = m2b;
    }

    // ---- decode: lane computes mean[lane] AND u[lane] (two chains, ILP)
    float dm = 0.0f, du = 0.0f;
    {
        const float* pd = Wdec + lane;
        const float* pu = Wunc + lane;
        for (int n = 0; n < HD; n++) {
            float mv = s_mem2[r][n];                     // broadcast read
            dm = fmaf(mv, pd[n*SS], dm);
            du = fmaf(mv, pu[n*SS], du);
        }
    }
    float mean = __fadd_rn(dm, bdec[lane]);
    float u    = __fadd_rn(du, bunc[lane]);

    // ---- sample next state
    float var = softplus_np(u);
    float sv  = sqrtf(__fadd_rn(var, 1e-8f));
    float nz  = noise[((size_t)cb*HH + h)*SS + lane];
    float ns  = __fadd_rn(mean, __fmul_rn(nz, sv));
    states[((size_t)h*CBR + cb)*SS + lane] = ns;

    // ---- reward for step h (fused): x = [ns, act]
    s_x[r][lane] = ns;
    if (lane < AA) s_x[r][SS + lane] = act[lane];

    float ra = 0.0f;
    for (int i = 0; i < SS + AA; i++)
        ra = fmaf(s_x[r][i], Wr1[i*RH + lane], ra);
    s_h[r][lane] = fmaxf(__fadd_rn(ra, br1[lane]), 0.0f);

    float rg = 0.0f;
    for (int i = 0; i < RH; i++)
        rg = fmaf(s_h[r][i], Wr2[i*RH + lane], rg);
    s_h2[r][lane] = fmaxf(__fadd_rn(rg, br2[lane]), 0.0f);

    // fold r_h (redundant across lanes via broadcast reads; lane 0 commits).
    // cum accumulates across the 10 dispatches in ascending-h order — the
    // same sequential __fadd_rn chain as the reference.
    float rr = 0.0f;
    for (int k = 0; k < RH; k++)
        rr = fmaf(s_h2[r][k], Wr3[k], rr);
    rr = __fadd_rn(rr, br3[0]);
    if (lane == 0)
        cum[cb] = (h == 0) ? rr : __fadd_rn(cum[cb], rr);
}

// One block per batch element b: f32 argmax over C (strict > = first max),
// gather best action. (Bit-exact, unchanged.)
__global__ __launch_bounds__(64) void select_kernel(
    const float* __restrict__ cum,      // [CB], cb = c*B + b
    const float* __restrict__ actions,  // [C,B,H,A]
    float* __restrict__ out)            // [B*H*A] actions then [B] values
{
    const int b = blockIdx.x;
    const int j = threadIdx.x;
    __shared__ int s_c;

    if (j == 0) {
        float best = cum[b];            // c = 0
        int bc = 0;
        for (int c = 1; c < CC; c++) {
            float v = cum[(size_t)c*BB + b];
            if (v > best) { best = v; bc = c; }
        }
        s_c = bc;
        out[(size_t)BB*HH*AA + b] = best;
    }
    __syncthreads();
    const int bc = s_c;
    const float* src = actions + ((size_t)bc*BB + b)*HH*AA;
    for (int i = j; i < HH*AA; i += 64) out[(size_t)b*HH*AA + i] = src[i];
}

extern "C" void kernel_launch(void* const* d_in, const int* in_sizes, int n_in,
                              void* d_out, int out_size, void* d_ws, size_t ws_size,
                              hipStream_t stream)
{
    const float* current_state = (const float*)d_in[0];
    const float* actions = (const float*)d_in[1];
    const float* noise   = (const float*)d_in[2];
    const float* Wse = (const float*)d_in[3];
    const float* bse = (const float*)d_in[4];
    const float* Wae = (const float*)d_in[5];
    const float* bae = (const float*)d_in[6];
    const float* W1  = (const float*)d_in[7];
    const float* b1  = (const float*)d_in[8];
    const float* W2  = (const float*)d_in[9];
    const float* b2  = (const float*)d_in[10];
    const float* Wdec = (const float*)d_in[11];
    const float* bdec = (const float*)d_in[12];
    const float* Wunc = (const float*)d_in[13];
    const float* bunc = (const float*)d_in[14];
    const float* Wr1 = (const float*)d_in[15];
    const float* br1 = (const float*)d_in[16];
    const float* Wr2 = (const float*)d_in[17];
    const float* br2 = (const float*)d_in[18];
    const float* Wr3 = (const float*)d_in[19];
    const float* br3 = (const float*)d_in[20];

    float* states = (float*)d_ws;                       // 10*5120*64 f32 = 13.1 MB
    float* cum    = states + (size_t)HH*CBR*SS;         // 5120 f32

    for (int h = 0; h < HH; h++) {
        world_kernel<<<CBR/RT, RT*64, 0, stream>>>(h, current_state, actions, noise,
            Wse, bse, Wae, bae, W1, b1, W2, b2, Wdec, bdec, Wunc, bunc,
            Wr1, br1, Wr2, br2, Wr3, br3, states, cum);
    }
    select_kernel<<<BB, 64, 0, stream>>>(cum, actions, (float*)d_out);
}